// Round 1
// baseline (1201.074 us; speedup 1.0000x reference)
//
#include <hip/hip_runtime.h>

// R6: edge kernel was DS-pipe-bound (448 DS/2 edges x 5.86 cyc = 427us exactly).
// Restructure: We2 GEMV hoisted to per-node precompute (P1/P2), EPW=8 edges/wave
// with K split across wave halves. DS/edge: 224 -> 50. Node kernel unchanged.

#define NPB 8
#define EPW 8

__device__ inline void atomAddF(float* p, float v) {
#if defined(__HIP_PLATFORM_AMD__)
    unsafeAtomicAdd(p, v);
#else
    atomicAdd(p, v);
#endif
}

// ---------------------------------------------------------------------------
// Prepass 1: per-TYPE halves of the We2 GEMV.
// Pt1[t][c] = emb[t,:] @ We2[0:32, c] + be2[c] ; Pt2[t][c] = emb[t,:] @ We2[32:64, c]
// ---------------------------------------------------------------------------
__global__ void ptype_kernel(const float* __restrict__ emb,
                             const float* __restrict__ We2,
                             const float* __restrict__ be2,
                             float* __restrict__ Pt1, float* __restrict__ Pt2) {
    const int c = threadIdx.x & 31;
    const int t8 = threadIdx.x >> 5;
    for (int tb = 0; tb < 95; tb += 8) {
        const int t = tb + t8;
        if (t < 95) {
            float p1 = 0.f, p2 = 0.f;
            for (int k = 0; k < 32; ++k) {
                const float z = emb[t * 32 + k];
                p1 = fmaf(z, We2[k * 32 + c], p1);
                p2 = fmaf(z, We2[(32 + k) * 32 + c], p2);
            }
            Pt1[t * 32 + c] = p1 + be2[c];
            Pt2[t * 32 + c] = p2;
        }
    }
}

// ---------------------------------------------------------------------------
// Prepass 2: zero the accumulator + gather per-node P1/P2 from per-type tables.
// ---------------------------------------------------------------------------
__global__ void prep_zero(const int* __restrict__ nt,
                          const float* __restrict__ Pt1, const float* __restrict__ Pt2,
                          float* __restrict__ acc,
                          float* __restrict__ P1, float* __restrict__ P2, int N) {
    const int i = blockIdx.x * 256 + threadIdx.x;
    if (i < N * 320) acc[i] = 0.0f;
    if (i < N * 32) {
        const int n = i >> 5, c = i & 31;
        const int t = nt[n];
        P1[i] = Pt1[t * 32 + c];
        P2[i] = Pt2[t * 32 + c];
    }
}

// ---------------------------------------------------------------------------
// Edge kernel: one wave handles EPW=8 edges per pass.
// lane = (c = lane&31 channel, h = lane>>5 K-half). Half h accumulates
// k in [32h, 32h+32). Weights (Wd1,Wd2,Wd3,We3) staged once in 32KB LDS;
// per k: 4 ds_read_b32 (base+imm) + 8 width-32 shuffle broadcasts + 32 FMA.
// Halves merged with one shfl_xor(32) per accumulator; epilogue processes
// edge pairs (half0 -> slot jj, half1 -> slot jj+4) so each atomic
// instruction covers 2 edges.
// ---------------------------------------------------------------------------
__global__ __launch_bounds__(256, 4) void edge_kernel(
    const float* __restrict__ edge_attr,    // [E][64]
    const float* __restrict__ bond_dist,    // [E]
    const float* __restrict__ bond_vec,     // [E][3]
    const int*   __restrict__ src,
    const int*   __restrict__ dst,
    const float* __restrict__ Wd1, const float* __restrict__ bd1,
    const float* __restrict__ Wd2, const float* __restrict__ bd2,
    const float* __restrict__ Wd3, const float* __restrict__ bd3,
    const float* __restrict__ We3, const float* __restrict__ be3,
    const float* __restrict__ P1,           // [N][32]  (Zij src-half, bias folded)
    const float* __restrict__ P2,           // [N][32]  (Zij dst-half)
    float* __restrict__ acc,                // [N][10][32] fp32, pre-zeroed
    float* __restrict__ efeat,              // [E][32]
    int E)
{
    __shared__ float sW[4][64][32];   // 0:Wd1 1:Wd2 2:Wd3 3:We3  (32 KB)
    const int tid = threadIdx.x;
    for (int i = tid; i < 4 * 2048; i += 256) {
        const int m = i >> 11, r = i & 2047;
        const float* W = (m == 0) ? Wd1 : (m == 1) ? Wd2 : (m == 2) ? Wd3 : We3;
        sW[m][r >> 5][r & 31] = W[r];
    }
    __syncthreads();

    const int lane = tid & 63;
    const int c = lane & 31;
    const int h = lane >> 5;
    const float bd1r = bd1[c], bd2r = bd2[c], bd3r = bd3[c], be3r = be3[c];
    const float* wbase = &sW[0][h * 32][c];   // + kk*32 (+ m*2048) -> imm offsets

    const int wid = __builtin_amdgcn_readfirstlane((blockIdx.x * 256 + tid) >> 6);
    const int nw = gridDim.x * 4;
    const int ngroups = (E + EPW - 1) / EPW;

    for (int g = wid; g < ngroups; g += nw) {
        const int base = g * EPW;

        // x rows: lane l of edge j's row -> one coalesced 256B load per edge
        float xr[EPW];
#pragma unroll
        for (int j = 0; j < EPW; ++j) {
            int e = base + j; if (e >= E) e = E - 1;
            xr[j] = edge_attr[(size_t)e * 64 + lane];
        }

        float A0[EPW], A1[EPW], A2[EPW], A3[EPW];
#pragma unroll
        for (int j = 0; j < EPW; ++j) { A0[j] = 0.f; A1[j] = 0.f; A2[j] = 0.f; A3[j] = 0.f; }

#pragma unroll
        for (int kk = 0; kk < 32; ++kk) {
            const float w0 = wbase[kk * 32];           // sW[0][h*32+kk][c]
            const float w1 = wbase[kk * 32 + 2048];
            const float w2 = wbase[kk * 32 + 4096];
            const float w3 = wbase[kk * 32 + 6144];
#pragma unroll
            for (int j = 0; j < EPW; ++j) {
                const float xb = __shfl(xr[j], kk, 32);  // half0: x[kk], half1: x[32+kk]
                A0[j] = fmaf(xb, w0, A0[j]);
                A1[j] = fmaf(xb, w1, A1[j]);
                A2[j] = fmaf(xb, w2, A2[j]);
                A3[j] = fmaf(xb, w3, A3[j]);
            }
        }

        // Epilogue over 4 pairs: half0 handles edge base+jj, half1 handles base+jj+4.
#pragma unroll
        for (int jj = 0; jj < 4; ++jj) {
            // exchange cross-half partials: send the partial of the OTHER half's edge
            const float sd0 = h ? A0[jj] : A0[jj + 4];
            const float sd1 = h ? A1[jj] : A1[jj + 4];
            const float sd2 = h ? A2[jj] : A2[jj + 4];
            const float sd3 = h ? A3[jj] : A3[jj + 4];
            const float mn0 = h ? A0[jj + 4] : A0[jj];
            const float mn1 = h ? A1[jj + 4] : A1[jj];
            const float mn2 = h ? A2[jj + 4] : A2[jj];
            const float mn3 = h ? A3[jj + 4] : A3[jj];
            const float t0 = mn0 + __shfl_xor(sd0, 32);
            const float t1 = mn1 + __shfl_xor(sd1, 32);
            const float t2 = mn2 + __shfl_xor(sd2, 32);
            const float t3 = mn3 + __shfl_xor(sd3, 32);

            const int e = base + jj + 4 * h;
            const bool val = (e < E);
            const int ec = val ? e : (E - 1);

            const float d = bond_dist[ec];
            const float C = (d <= 5.0f) ? 0.5f * (cosf(3.14159265358979323846f * d / 5.0f) + 1.0f) : 0.0f;
            float v0 = bond_vec[3 * (size_t)ec + 0];
            float v1 = bond_vec[3 * (size_t)ec + 1];
            float v2 = bond_vec[3 * (size_t)ec + 2];
            const float inv = 1.0f / sqrtf(v0 * v0 + v1 * v1 + v2 * v2);
            v0 *= inv; v1 *= inv; v2 *= inv;
            const float tr3 = (v0 * v0 + v1 * v1 + v2 * v2) * (1.0f / 3.0f);
            const float y00 = v0 * v0 - tr3, y11 = v1 * v1 - tr3, y22 = v2 * v2 - tr3;
            const float y01 = v0 * v1, y02 = v0 * v2, y12 = v1 * v2;

            const int si = src[ec], di = dst[ec];
            const float az = P1[(size_t)si * 32 + c] + P2[(size_t)di * 32 + c];

            const float a1v = t0 + bd1r;
            const float a2v = t1 + bd2r;
            const float a3v = t2 + bd3r;
            const float a4v = t3 + be3r;
            const float w1v = a1v * C, w2v = a2v * C, w3v = a3v * C;
            const float fI = az * w1v, fA = az * w2v, fS = az * w3v;

            if (val) {
                efeat[(size_t)e * 32 + c] = a4v;
                float* ap = acc + (size_t)di * 320 + c;
                atomAddF(ap,       fI);
                atomAddF(ap + 32,  fA * v0);
                atomAddF(ap + 64,  fA * v1);
                atomAddF(ap + 96,  fA * v2);
                atomAddF(ap + 128, fS * y00);
                atomAddF(ap + 160, fS * y01);
                atomAddF(ap + 192, fS * y02);
                atomAddF(ap + 224, fS * y11);
                atomAddF(ap + 256, fS * y12);
                atomAddF(ap + 288, fS * y22);
            }
        }
    }
}

// ---------------------------------------------------------------------------
// Node kernel: 8 nodes/block, 32 threads (=channels) per node. (unchanged)
// ---------------------------------------------------------------------------
__global__ __launch_bounds__(256) void node_kernel(
    const float* __restrict__ acc,          // [N][10][32]
    const float* __restrict__ Wt0, const float* __restrict__ Wt1, const float* __restrict__ Wt2,
    const float* __restrict__ Ws1, const float* __restrict__ bs1,
    const float* __restrict__ Ws2, const float* __restrict__ bs2,
    const float* __restrict__ lng, const float* __restrict__ lnb,
    float* __restrict__ xout,               // [N][32][3][3]
    int N)
{
    __shared__ float wt[3][32][32];
    __shared__ float ws1[32][64];
    __shared__ float ws2[64][96];
    __shared__ float sb1[64], sb2[96], sg[32], sbv[32];
    __shared__ float accS[NPB][10][32];
    __shared__ float nrmS[NPB][32];
    __shared__ float h1S[NPB][64];

    const int tid = threadIdx.x;
    for (int i = tid; i < 1024; i += 256) wt[0][i >> 5][i & 31] = Wt0[i];
    for (int i = tid; i < 1024; i += 256) wt[1][i >> 5][i & 31] = Wt1[i];
    for (int i = tid; i < 1024; i += 256) wt[2][i >> 5][i & 31] = Wt2[i];
    for (int i = tid; i < 2048; i += 256) ws1[i >> 6][i & 63] = Ws1[i];
    for (int i = tid; i < 6144; i += 256) ws2[i / 96][i % 96] = Ws2[i];
    if (tid < 64) sb1[tid] = bs1[tid];
    if (tid < 96) sb2[tid] = bs2[tid];
    if (tid < 32) { sg[tid] = lng[tid]; sbv[tid] = lnb[tid]; }
    __syncthreads();

    const int ln_ = tid >> 5, u = tid & 31;
    const int n = blockIdx.x * NPB + ln_;
    const bool valid = n < N;

    float c0 = 0, a0 = 0, a1 = 0, a2 = 0, s00 = 0, s01 = 0, s02 = 0, s11 = 0, s12 = 0, s22 = 0;
    if (valid) {
        const float* ap = acc + (size_t)n * 320 + u;
        c0 = ap[0];  a0 = ap[32];  a1 = ap[64];  a2 = ap[96];
        s00 = ap[128]; s01 = ap[160]; s02 = ap[192];
        s11 = ap[224]; s12 = ap[256]; s22 = ap[288];
    }
    accS[ln_][0][u] = c0;  accS[ln_][1][u] = a0;  accS[ln_][2][u] = a1;  accS[ln_][3][u] = a2;
    accS[ln_][4][u] = s00; accS[ln_][5][u] = s01; accS[ln_][6][u] = s02;
    accS[ln_][7][u] = s11; accS[ln_][8][u] = s12; accS[ln_][9][u] = s22;

    float m00 = c0 + s00, m11 = c0 + s11, m22 = c0 + s22;
    float nrm = m00 * m00 + m11 * m11 + m22 * m22
              + 2.0f * (s01 * s01 + a2 * a2 + s02 * s02 + a1 * a1 + s12 * s12 + a0 * a0);

    float sum = nrm;
#pragma unroll
    for (int o = 16; o >= 1; o >>= 1) sum += __shfl_xor(sum, o, 32);
    float mu = sum * (1.0f / 32.0f);
    float dv = nrm - mu;
    float vs = dv * dv;
#pragma unroll
    for (int o = 16; o >= 1; o >>= 1) vs += __shfl_xor(vs, o, 32);
    float var = vs * (1.0f / 32.0f);
    float nl = dv * rsqrtf(var + 1e-5f) * sg[u] + sbv[u];
    nrmS[ln_][u] = nl;
    __syncthreads();

    float h1a = sb1[u], h1b = sb1[u + 32];
#pragma unroll
    for (int k = 0; k < 32; ++k) {
        float x = nrmS[ln_][k];
        h1a += x * ws1[k][u];
        h1b += x * ws1[k][u + 32];
    }
    h1a = h1a / (1.0f + __expf(-h1a));
    h1b = h1b / (1.0f + __expf(-h1b));
    h1S[ln_][u] = h1a; h1S[ln_][u + 32] = h1b;
    __syncthreads();

    float f0 = sb2[3 * u], f1 = sb2[3 * u + 1], f2 = sb2[3 * u + 2];
#pragma unroll
    for (int k = 0; k < 64; ++k) {
        float hh = h1S[ln_][k];
        f0 += hh * ws2[k][3 * u];
        f1 += hh * ws2[k][3 * u + 1];
        f2 += hh * ws2[k][3 * u + 2];
    }
    f0 = f0 / (1.0f + __expf(-f0));
    f1 = f1 / (1.0f + __expf(-f1));
    f2 = f2 / (1.0f + __expf(-f2));

    float m0 = 0, ma0 = 0, ma1 = 0, ma2 = 0;
    float ms00 = 0, ms01 = 0, ms02 = 0, ms11 = 0, ms12 = 0, ms22 = 0;
#pragma unroll
    for (int k = 0; k < 32; ++k) {
        float w0 = wt[0][k][u], w1 = wt[1][k][u], w2 = wt[2][k][u];
        m0   += accS[ln_][0][k] * w0;
        ma0  += accS[ln_][1][k] * w1;
        ma1  += accS[ln_][2][k] * w1;
        ma2  += accS[ln_][3][k] * w1;
        ms00 += accS[ln_][4][k] * w2;
        ms01 += accS[ln_][5][k] * w2;
        ms02 += accS[ln_][6][k] * w2;
        ms11 += accS[ln_][7][k] * w2;
        ms12 += accS[ln_][8][k] * w2;
        ms22 += accS[ln_][9][k] * w2;
    }
    if (valid) {
        float* xp = xout + (size_t)n * 288 + u * 9;
        xp[0] = f0 * m0 + f2 * ms00;
        xp[1] = f1 * (-ma2) + f2 * ms01;
        xp[2] = f1 * ( ma1) + f2 * ms02;
        xp[3] = f1 * ( ma2) + f2 * ms01;
        xp[4] = f0 * m0 + f2 * ms11;
        xp[5] = f1 * (-ma0) + f2 * ms12;
        xp[6] = f1 * (-ma1) + f2 * ms02;
        xp[7] = f1 * ( ma0) + f2 * ms12;
        xp[8] = f0 * m0 + f2 * ms22;
    }
}

extern "C" void kernel_launch(void* const* d_in, const int* in_sizes, int n_in,
                              void* d_out, int out_size, void* d_ws, size_t ws_size,
                              hipStream_t stream) {
    const int N = in_sizes[0];
    const int E = in_sizes[2];

    // Workspace layout (fp32): acc N*320 | P1 N*32 | P2 N*32 | Pt1 95*32 | Pt2 95*32
    float* acc = (float*)d_ws;
    float* P1  = acc + (size_t)N * 320;
    float* P2  = P1 + (size_t)N * 32;
    float* Pt1 = P2 + (size_t)N * 32;
    float* Pt2 = Pt1 + 95 * 32;

    float* xout  = (float*)d_out;              // [N][32][3][3] f32
    float* efeat = xout + (size_t)N * 288;     // [E][32] f32

    ptype_kernel<<<1, 256, 0, stream>>>(
        (const float*)d_in[6], (const float*)d_in[13], (const float*)d_in[14], Pt1, Pt2);

    prep_zero<<<(N * 320 + 255) / 256, 256, 0, stream>>>(
        (const int*)d_in[0], Pt1, Pt2, acc, P1, P2, N);

    edge_kernel<<<1024, 256, 0, stream>>>(
        (const float*)d_in[1], (const float*)d_in[2], (const float*)d_in[3],
        (const int*)d_in[4], (const int*)d_in[5],
        (const float*)d_in[7],  (const float*)d_in[8],
        (const float*)d_in[9],  (const float*)d_in[10],
        (const float*)d_in[11], (const float*)d_in[12],
        (const float*)d_in[15], (const float*)d_in[16],
        P1, P2, acc, efeat, E);

    node_kernel<<<(N + NPB - 1) / NPB, 256, 0, stream>>>(
        acc,
        (const float*)d_in[17], (const float*)d_in[18], (const float*)d_in[19],
        (const float*)d_in[20], (const float*)d_in[21],
        (const float*)d_in[22], (const float*)d_in[23],
        (const float*)d_in[24], (const float*)d_in[25],
        xout, N);
}

// Round 2
// 869.842 us; speedup vs baseline: 1.3808x; 1.3808x over previous
//
#include <hip/hip_runtime.h>

// R7: R6's restructure was correct but __launch_bounds__(256,4) clamped VGPR to 64
// -> accumulator spills -> 2.9 GB scratch traffic (FETCH 1.6GB, VALUBusy 7%).
// Single change: launch_bounds (256,2) so the EPW=8 kk-loop fits in registers.

#define NPB 8
#define EPW 8

__device__ inline void atomAddF(float* p, float v) {
#if defined(__HIP_PLATFORM_AMD__)
    unsafeAtomicAdd(p, v);
#else
    atomicAdd(p, v);
#endif
}

// ---------------------------------------------------------------------------
// Prepass 1: per-TYPE halves of the We2 GEMV.
// Pt1[t][c] = emb[t,:] @ We2[0:32, c] + be2[c] ; Pt2[t][c] = emb[t,:] @ We2[32:64, c]
// ---------------------------------------------------------------------------
__global__ void ptype_kernel(const float* __restrict__ emb,
                             const float* __restrict__ We2,
                             const float* __restrict__ be2,
                             float* __restrict__ Pt1, float* __restrict__ Pt2) {
    const int c = threadIdx.x & 31;
    const int t8 = threadIdx.x >> 5;
    for (int tb = 0; tb < 95; tb += 8) {
        const int t = tb + t8;
        if (t < 95) {
            float p1 = 0.f, p2 = 0.f;
            for (int k = 0; k < 32; ++k) {
                const float z = emb[t * 32 + k];
                p1 = fmaf(z, We2[k * 32 + c], p1);
                p2 = fmaf(z, We2[(32 + k) * 32 + c], p2);
            }
            Pt1[t * 32 + c] = p1 + be2[c];
            Pt2[t * 32 + c] = p2;
        }
    }
}

// ---------------------------------------------------------------------------
// Prepass 2: zero the accumulator + gather per-node P1/P2 from per-type tables.
// ---------------------------------------------------------------------------
__global__ void prep_zero(const int* __restrict__ nt,
                          const float* __restrict__ Pt1, const float* __restrict__ Pt2,
                          float* __restrict__ acc,
                          float* __restrict__ P1, float* __restrict__ P2, int N) {
    const int i = blockIdx.x * 256 + threadIdx.x;
    if (i < N * 320) acc[i] = 0.0f;
    if (i < N * 32) {
        const int n = i >> 5, c = i & 31;
        const int t = nt[n];
        P1[i] = Pt1[t * 32 + c];
        P2[i] = Pt2[t * 32 + c];
    }
}

// ---------------------------------------------------------------------------
// Edge kernel: one wave handles EPW=8 edges per pass.
// lane = (c = lane&31 channel, h = lane>>5 K-half). Half h accumulates
// k in [32h, 32h+32). Weights (Wd1,Wd2,Wd3,We3) staged once in 32KB LDS;
// per k: 4 ds_read_b32 (base+imm) + 8 width-32 shuffle broadcasts + 32 FMA.
// Halves merged with one shfl_xor(32) per accumulator; epilogue processes
// edge pairs (half0 -> slot jj, half1 -> slot jj+4) so each atomic
// instruction covers 2 edges.
// launch_bounds (256,2): VGPR cap 128 (need ~80-100); (256,4) spilled. [R7]
// ---------------------------------------------------------------------------
__global__ __launch_bounds__(256, 2) void edge_kernel(
    const float* __restrict__ edge_attr,    // [E][64]
    const float* __restrict__ bond_dist,    // [E]
    const float* __restrict__ bond_vec,     // [E][3]
    const int*   __restrict__ src,
    const int*   __restrict__ dst,
    const float* __restrict__ Wd1, const float* __restrict__ bd1,
    const float* __restrict__ Wd2, const float* __restrict__ bd2,
    const float* __restrict__ Wd3, const float* __restrict__ bd3,
    const float* __restrict__ We3, const float* __restrict__ be3,
    const float* __restrict__ P1,           // [N][32]  (Zij src-half, bias folded)
    const float* __restrict__ P2,           // [N][32]  (Zij dst-half)
    float* __restrict__ acc,                // [N][10][32] fp32, pre-zeroed
    float* __restrict__ efeat,              // [E][32]
    int E)
{
    __shared__ float sW[4][64][32];   // 0:Wd1 1:Wd2 2:Wd3 3:We3  (32 KB)
    const int tid = threadIdx.x;
    for (int i = tid; i < 4 * 2048; i += 256) {
        const int m = i >> 11, r = i & 2047;
        const float* W = (m == 0) ? Wd1 : (m == 1) ? Wd2 : (m == 2) ? Wd3 : We3;
        sW[m][r >> 5][r & 31] = W[r];
    }
    __syncthreads();

    const int lane = tid & 63;
    const int c = lane & 31;
    const int h = lane >> 5;
    const float bd1r = bd1[c], bd2r = bd2[c], bd3r = bd3[c], be3r = be3[c];
    const float* wbase = &sW[0][h * 32][c];   // + kk*32 (+ m*2048) -> imm offsets

    const int wid = __builtin_amdgcn_readfirstlane((blockIdx.x * 256 + tid) >> 6);
    const int nw = gridDim.x * 4;
    const int ngroups = (E + EPW - 1) / EPW;

    for (int g = wid; g < ngroups; g += nw) {
        const int base = g * EPW;

        // x rows: lane l of edge j's row -> one coalesced 256B load per edge
        float xr[EPW];
#pragma unroll
        for (int j = 0; j < EPW; ++j) {
            int e = base + j; if (e >= E) e = E - 1;
            xr[j] = edge_attr[(size_t)e * 64 + lane];
        }

        float A0[EPW], A1[EPW], A2[EPW], A3[EPW];
#pragma unroll
        for (int j = 0; j < EPW; ++j) { A0[j] = 0.f; A1[j] = 0.f; A2[j] = 0.f; A3[j] = 0.f; }

#pragma unroll
        for (int kk = 0; kk < 32; ++kk) {
            const float w0 = wbase[kk * 32];           // sW[0][h*32+kk][c]
            const float w1 = wbase[kk * 32 + 2048];
            const float w2 = wbase[kk * 32 + 4096];
            const float w3 = wbase[kk * 32 + 6144];
#pragma unroll
            for (int j = 0; j < EPW; ++j) {
                const float xb = __shfl(xr[j], kk, 32);  // half0: x[kk], half1: x[32+kk]
                A0[j] = fmaf(xb, w0, A0[j]);
                A1[j] = fmaf(xb, w1, A1[j]);
                A2[j] = fmaf(xb, w2, A2[j]);
                A3[j] = fmaf(xb, w3, A3[j]);
            }
        }

        // Epilogue over 4 pairs: half0 handles edge base+jj, half1 handles base+jj+4.
#pragma unroll
        for (int jj = 0; jj < 4; ++jj) {
            // exchange cross-half partials: send the partial of the OTHER half's edge
            const float sd0 = h ? A0[jj] : A0[jj + 4];
            const float sd1 = h ? A1[jj] : A1[jj + 4];
            const float sd2 = h ? A2[jj] : A2[jj + 4];
            const float sd3 = h ? A3[jj] : A3[jj + 4];
            const float mn0 = h ? A0[jj + 4] : A0[jj];
            const float mn1 = h ? A1[jj + 4] : A1[jj];
            const float mn2 = h ? A2[jj + 4] : A2[jj];
            const float mn3 = h ? A3[jj + 4] : A3[jj];
            const float t0 = mn0 + __shfl_xor(sd0, 32);
            const float t1 = mn1 + __shfl_xor(sd1, 32);
            const float t2 = mn2 + __shfl_xor(sd2, 32);
            const float t3 = mn3 + __shfl_xor(sd3, 32);

            const int e = base + jj + 4 * h;
            const bool val = (e < E);
            const int ec = val ? e : (E - 1);

            const float d = bond_dist[ec];
            const float C = (d <= 5.0f) ? 0.5f * (cosf(3.14159265358979323846f * d / 5.0f) + 1.0f) : 0.0f;
            float v0 = bond_vec[3 * (size_t)ec + 0];
            float v1 = bond_vec[3 * (size_t)ec + 1];
            float v2 = bond_vec[3 * (size_t)ec + 2];
            const float inv = 1.0f / sqrtf(v0 * v0 + v1 * v1 + v2 * v2);
            v0 *= inv; v1 *= inv; v2 *= inv;
            const float tr3 = (v0 * v0 + v1 * v1 + v2 * v2) * (1.0f / 3.0f);
            const float y00 = v0 * v0 - tr3, y11 = v1 * v1 - tr3, y22 = v2 * v2 - tr3;
            const float y01 = v0 * v1, y02 = v0 * v2, y12 = v1 * v2;

            const int si = src[ec], di = dst[ec];
            const float az = P1[(size_t)si * 32 + c] + P2[(size_t)di * 32 + c];

            const float a1v = t0 + bd1r;
            const float a2v = t1 + bd2r;
            const float a3v = t2 + bd3r;
            const float a4v = t3 + be3r;
            const float w1v = a1v * C, w2v = a2v * C, w3v = a3v * C;
            const float fI = az * w1v, fA = az * w2v, fS = az * w3v;

            if (val) {
                efeat[(size_t)e * 32 + c] = a4v;
                float* ap = acc + (size_t)di * 320 + c;
                atomAddF(ap,       fI);
                atomAddF(ap + 32,  fA * v0);
                atomAddF(ap + 64,  fA * v1);
                atomAddF(ap + 96,  fA * v2);
                atomAddF(ap + 128, fS * y00);
                atomAddF(ap + 160, fS * y01);
                atomAddF(ap + 192, fS * y02);
                atomAddF(ap + 224, fS * y11);
                atomAddF(ap + 256, fS * y12);
                atomAddF(ap + 288, fS * y22);
            }
        }
    }
}

// ---------------------------------------------------------------------------
// Node kernel: 8 nodes/block, 32 threads (=channels) per node. (unchanged)
// ---------------------------------------------------------------------------
__global__ __launch_bounds__(256) void node_kernel(
    const float* __restrict__ acc,          // [N][10][32]
    const float* __restrict__ Wt0, const float* __restrict__ Wt1, const float* __restrict__ Wt2,
    const float* __restrict__ Ws1, const float* __restrict__ bs1,
    const float* __restrict__ Ws2, const float* __restrict__ bs2,
    const float* __restrict__ lng, const float* __restrict__ lnb,
    float* __restrict__ xout,               // [N][32][3][3]
    int N)
{
    __shared__ float wt[3][32][32];
    __shared__ float ws1[32][64];
    __shared__ float ws2[64][96];
    __shared__ float sb1[64], sb2[96], sg[32], sbv[32];
    __shared__ float accS[NPB][10][32];
    __shared__ float nrmS[NPB][32];
    __shared__ float h1S[NPB][64];

    const int tid = threadIdx.x;
    for (int i = tid; i < 1024; i += 256) wt[0][i >> 5][i & 31] = Wt0[i];
    for (int i = tid; i < 1024; i += 256) wt[1][i >> 5][i & 31] = Wt1[i];
    for (int i = tid; i < 1024; i += 256) wt[2][i >> 5][i & 31] = Wt2[i];
    for (int i = tid; i < 2048; i += 256) ws1[i >> 6][i & 63] = Ws1[i];
    for (int i = tid; i < 6144; i += 256) ws2[i / 96][i % 96] = Ws2[i];
    if (tid < 64) sb1[tid] = bs1[tid];
    if (tid < 96) sb2[tid] = bs2[tid];
    if (tid < 32) { sg[tid] = lng[tid]; sbv[tid] = lnb[tid]; }
    __syncthreads();

    const int ln_ = tid >> 5, u = tid & 31;
    const int n = blockIdx.x * NPB + ln_;
    const bool valid = n < N;

    float c0 = 0, a0 = 0, a1 = 0, a2 = 0, s00 = 0, s01 = 0, s02 = 0, s11 = 0, s12 = 0, s22 = 0;
    if (valid) {
        const float* ap = acc + (size_t)n * 320 + u;
        c0 = ap[0];  a0 = ap[32];  a1 = ap[64];  a2 = ap[96];
        s00 = ap[128]; s01 = ap[160]; s02 = ap[192];
        s11 = ap[224]; s12 = ap[256]; s22 = ap[288];
    }
    accS[ln_][0][u] = c0;  accS[ln_][1][u] = a0;  accS[ln_][2][u] = a1;  accS[ln_][3][u] = a2;
    accS[ln_][4][u] = s00; accS[ln_][5][u] = s01; accS[ln_][6][u] = s02;
    accS[ln_][7][u] = s11; accS[ln_][8][u] = s12; accS[ln_][9][u] = s22;

    float m00 = c0 + s00, m11 = c0 + s11, m22 = c0 + s22;
    float nrm = m00 * m00 + m11 * m11 + m22 * m22
              + 2.0f * (s01 * s01 + a2 * a2 + s02 * s02 + a1 * a1 + s12 * s12 + a0 * a0);

    float sum = nrm;
#pragma unroll
    for (int o = 16; o >= 1; o >>= 1) sum += __shfl_xor(sum, o, 32);
    float mu = sum * (1.0f / 32.0f);
    float dv = nrm - mu;
    float vs = dv * dv;
#pragma unroll
    for (int o = 16; o >= 1; o >>= 1) vs += __shfl_xor(vs, o, 32);
    float var = vs * (1.0f / 32.0f);
    float nl = dv * rsqrtf(var + 1e-5f) * sg[u] + sbv[u];
    nrmS[ln_][u] = nl;
    __syncthreads();

    float h1a = sb1[u], h1b = sb1[u + 32];
#pragma unroll
    for (int k = 0; k < 32; ++k) {
        float x = nrmS[ln_][k];
        h1a += x * ws1[k][u];
        h1b += x * ws1[k][u + 32];
    }
    h1a = h1a / (1.0f + __expf(-h1a));
    h1b = h1b / (1.0f + __expf(-h1b));
    h1S[ln_][u] = h1a; h1S[ln_][u + 32] = h1b;
    __syncthreads();

    float f0 = sb2[3 * u], f1 = sb2[3 * u + 1], f2 = sb2[3 * u + 2];
#pragma unroll
    for (int k = 0; k < 64; ++k) {
        float hh = h1S[ln_][k];
        f0 += hh * ws2[k][3 * u];
        f1 += hh * ws2[k][3 * u + 1];
        f2 += hh * ws2[k][3 * u + 2];
    }
    f0 = f0 / (1.0f + __expf(-f0));
    f1 = f1 / (1.0f + __expf(-f1));
    f2 = f2 / (1.0f + __expf(-f2));

    float m0 = 0, ma0 = 0, ma1 = 0, ma2 = 0;
    float ms00 = 0, ms01 = 0, ms02 = 0, ms11 = 0, ms12 = 0, ms22 = 0;
#pragma unroll
    for (int k = 0; k < 32; ++k) {
        float w0 = wt[0][k][u], w1 = wt[1][k][u], w2 = wt[2][k][u];
        m0   += accS[ln_][0][k] * w0;
        ma0  += accS[ln_][1][k] * w1;
        ma1  += accS[ln_][2][k] * w1;
        ma2  += accS[ln_][3][k] * w1;
        ms00 += accS[ln_][4][k] * w2;
        ms01 += accS[ln_][5][k] * w2;
        ms02 += accS[ln_][6][k] * w2;
        ms11 += accS[ln_][7][k] * w2;
        ms12 += accS[ln_][8][k] * w2;
        ms22 += accS[ln_][9][k] * w2;
    }
    if (valid) {
        float* xp = xout + (size_t)n * 288 + u * 9;
        xp[0] = f0 * m0 + f2 * ms00;
        xp[1] = f1 * (-ma2) + f2 * ms01;
        xp[2] = f1 * ( ma1) + f2 * ms02;
        xp[3] = f1 * ( ma2) + f2 * ms01;
        xp[4] = f0 * m0 + f2 * ms11;
        xp[5] = f1 * (-ma0) + f2 * ms12;
        xp[6] = f1 * (-ma1) + f2 * ms02;
        xp[7] = f1 * ( ma0) + f2 * ms12;
        xp[8] = f0 * m0 + f2 * ms22;
    }
}

extern "C" void kernel_launch(void* const* d_in, const int* in_sizes, int n_in,
                              void* d_out, int out_size, void* d_ws, size_t ws_size,
                              hipStream_t stream) {
    const int N = in_sizes[0];
    const int E = in_sizes[2];

    // Workspace layout (fp32): acc N*320 | P1 N*32 | P2 N*32 | Pt1 95*32 | Pt2 95*32
    float* acc = (float*)d_ws;
    float* P1  = acc + (size_t)N * 320;
    float* P2  = P1 + (size_t)N * 32;
    float* Pt1 = P2 + (size_t)N * 32;
    float* Pt2 = Pt1 + 95 * 32;

    float* xout  = (float*)d_out;              // [N][32][3][3] f32
    float* efeat = xout + (size_t)N * 288;     // [E][32] f32

    ptype_kernel<<<1, 256, 0, stream>>>(
        (const float*)d_in[6], (const float*)d_in[13], (const float*)d_in[14], Pt1, Pt2);

    prep_zero<<<(N * 320 + 255) / 256, 256, 0, stream>>>(
        (const int*)d_in[0], Pt1, Pt2, acc, P1, P2, N);

    edge_kernel<<<1024, 256, 0, stream>>>(
        (const float*)d_in[1], (const float*)d_in[2], (const float*)d_in[3],
        (const int*)d_in[4], (const int*)d_in[5],
        (const float*)d_in[7],  (const float*)d_in[8],
        (const float*)d_in[9],  (const float*)d_in[10],
        (const float*)d_in[11], (const float*)d_in[12],
        (const float*)d_in[15], (const float*)d_in[16],
        P1, P2, acc, efeat, E);

    node_kernel<<<(N + NPB - 1) / NPB, 256, 0, stream>>>(
        acc,
        (const float*)d_in[17], (const float*)d_in[18], (const float*)d_in[19],
        (const float*)d_in[20], (const float*)d_in[21],
        (const float*)d_in[22], (const float*)d_in[23],
        (const float*)d_in[24], (const float*)d_in[25],
        xout, N);
}

// Round 3
// 428.339 us; speedup vs baseline: 2.8040x; 2.0307x over previous
//
#include <hip/hip_runtime.h>

// R8: R7 still spilled — VGPR pinned at cap (128), FETCH/WRITE ~0.5/0.7 GB over
// algorithmic. Fix: uncap VGPRs (launch_bounds(256) only) + partial unroll (8)
// on the kk loop so the scheduler can't inflate in-flight pressure past the file.

#define NPB 8
#define EPW 8

__device__ inline void atomAddF(float* p, float v) {
#if defined(__HIP_PLATFORM_AMD__)
    unsafeAtomicAdd(p, v);
#else
    atomicAdd(p, v);
#endif
}

// ---------------------------------------------------------------------------
// Prepass 1: per-TYPE halves of the We2 GEMV.
// Pt1[t][c] = emb[t,:] @ We2[0:32, c] + be2[c] ; Pt2[t][c] = emb[t,:] @ We2[32:64, c]
// ---------------------------------------------------------------------------
__global__ void ptype_kernel(const float* __restrict__ emb,
                             const float* __restrict__ We2,
                             const float* __restrict__ be2,
                             float* __restrict__ Pt1, float* __restrict__ Pt2) {
    const int c = threadIdx.x & 31;
    const int t8 = threadIdx.x >> 5;
    for (int tb = 0; tb < 95; tb += 8) {
        const int t = tb + t8;
        if (t < 95) {
            float p1 = 0.f, p2 = 0.f;
            for (int k = 0; k < 32; ++k) {
                const float z = emb[t * 32 + k];
                p1 = fmaf(z, We2[k * 32 + c], p1);
                p2 = fmaf(z, We2[(32 + k) * 32 + c], p2);
            }
            Pt1[t * 32 + c] = p1 + be2[c];
            Pt2[t * 32 + c] = p2;
        }
    }
}

// ---------------------------------------------------------------------------
// Prepass 2: zero the accumulator + gather per-node P1/P2 from per-type tables.
// ---------------------------------------------------------------------------
__global__ void prep_zero(const int* __restrict__ nt,
                          const float* __restrict__ Pt1, const float* __restrict__ Pt2,
                          float* __restrict__ acc,
                          float* __restrict__ P1, float* __restrict__ P2, int N) {
    const int i = blockIdx.x * 256 + threadIdx.x;
    if (i < N * 320) acc[i] = 0.0f;
    if (i < N * 32) {
        const int n = i >> 5, c = i & 31;
        const int t = nt[n];
        P1[i] = Pt1[t * 32 + c];
        P2[i] = Pt2[t * 32 + c];
    }
}

// ---------------------------------------------------------------------------
// Edge kernel: one wave handles EPW=8 edges per pass.
// lane = (c = lane&31 channel, h = lane>>5 K-half). Half h accumulates
// k in [32h, 32h+32). Weights (Wd1,Wd2,Wd3,We3) staged once in 32KB LDS;
// per k: 4 ds_read_b32 + 8 width-32 shuffle broadcasts + 32 FMA.
// VGPR note [R8]: do NOT cap VGPRs — (256,4) and (256,2) both pinned the
// allocator at the cap and spilled the 32 accumulators (GBs of scratch).
// kk unroll is 8 (not full) to bound scheduler-induced pressure.
// ---------------------------------------------------------------------------
__global__ __launch_bounds__(256) void edge_kernel(
    const float* __restrict__ edge_attr,    // [E][64]
    const float* __restrict__ bond_dist,    // [E]
    const float* __restrict__ bond_vec,     // [E][3]
    const int*   __restrict__ src,
    const int*   __restrict__ dst,
    const float* __restrict__ Wd1, const float* __restrict__ bd1,
    const float* __restrict__ Wd2, const float* __restrict__ bd2,
    const float* __restrict__ Wd3, const float* __restrict__ bd3,
    const float* __restrict__ We3, const float* __restrict__ be3,
    const float* __restrict__ P1,           // [N][32]  (Zij src-half, bias folded)
    const float* __restrict__ P2,           // [N][32]  (Zij dst-half)
    float* __restrict__ acc,                // [N][10][32] fp32, pre-zeroed
    float* __restrict__ efeat,              // [E][32]
    int E)
{
    __shared__ float sW[4][64][32];   // 0:Wd1 1:Wd2 2:Wd3 3:We3  (32 KB)
    const int tid = threadIdx.x;
    for (int i = tid; i < 4 * 2048; i += 256) {
        const int m = i >> 11, r = i & 2047;
        const float* W = (m == 0) ? Wd1 : (m == 1) ? Wd2 : (m == 2) ? Wd3 : We3;
        sW[m][r >> 5][r & 31] = W[r];
    }
    __syncthreads();

    const int lane = tid & 63;
    const int c = lane & 31;
    const int h = lane >> 5;
    const float bd1r = bd1[c], bd2r = bd2[c], bd3r = bd3[c], be3r = be3[c];
    const float* wbase = &sW[0][h * 32][c];   // + kk*32 (+ m*2048) -> imm offsets

    const int wid = __builtin_amdgcn_readfirstlane((blockIdx.x * 256 + tid) >> 6);
    const int nw = gridDim.x * 4;
    const int ngroups = (E + EPW - 1) / EPW;

    for (int g = wid; g < ngroups; g += nw) {
        const int base = g * EPW;

        // x rows: lane l of edge j's row -> one coalesced 256B load per edge
        float xr[EPW];
#pragma unroll
        for (int j = 0; j < EPW; ++j) {
            int e = base + j; if (e >= E) e = E - 1;
            xr[j] = edge_attr[(size_t)e * 64 + lane];
        }

        float A0[EPW], A1[EPW], A2[EPW], A3[EPW];
#pragma unroll
        for (int j = 0; j < EPW; ++j) { A0[j] = 0.f; A1[j] = 0.f; A2[j] = 0.f; A3[j] = 0.f; }

#pragma unroll 8
        for (int kk = 0; kk < 32; ++kk) {
            const float w0 = wbase[kk * 32];           // sW[0][h*32+kk][c]
            const float w1 = wbase[kk * 32 + 2048];
            const float w2 = wbase[kk * 32 + 4096];
            const float w3 = wbase[kk * 32 + 6144];
#pragma unroll
            for (int j = 0; j < EPW; ++j) {
                const float xb = __shfl(xr[j], kk, 32);  // half0: x[kk], half1: x[32+kk]
                A0[j] = fmaf(xb, w0, A0[j]);
                A1[j] = fmaf(xb, w1, A1[j]);
                A2[j] = fmaf(xb, w2, A2[j]);
                A3[j] = fmaf(xb, w3, A3[j]);
            }
        }

        // Epilogue over 4 pairs: half0 handles edge base+jj, half1 handles base+jj+4.
#pragma unroll
        for (int jj = 0; jj < 4; ++jj) {
            // exchange cross-half partials: send the partial of the OTHER half's edge
            const float sd0 = h ? A0[jj] : A0[jj + 4];
            const float sd1 = h ? A1[jj] : A1[jj + 4];
            const float sd2 = h ? A2[jj] : A2[jj + 4];
            const float sd3 = h ? A3[jj] : A3[jj + 4];
            const float mn0 = h ? A0[jj + 4] : A0[jj];
            const float mn1 = h ? A1[jj + 4] : A1[jj];
            const float mn2 = h ? A2[jj + 4] : A2[jj];
            const float mn3 = h ? A3[jj + 4] : A3[jj];
            const float t0 = mn0 + __shfl_xor(sd0, 32);
            const float t1 = mn1 + __shfl_xor(sd1, 32);
            const float t2 = mn2 + __shfl_xor(sd2, 32);
            const float t3 = mn3 + __shfl_xor(sd3, 32);

            const int e = base + jj + 4 * h;
            const bool val = (e < E);
            const int ec = val ? e : (E - 1);

            const float d = bond_dist[ec];
            const float C = (d <= 5.0f) ? 0.5f * (cosf(3.14159265358979323846f * d / 5.0f) + 1.0f) : 0.0f;
            float v0 = bond_vec[3 * (size_t)ec + 0];
            float v1 = bond_vec[3 * (size_t)ec + 1];
            float v2 = bond_vec[3 * (size_t)ec + 2];
            const float inv = 1.0f / sqrtf(v0 * v0 + v1 * v1 + v2 * v2);
            v0 *= inv; v1 *= inv; v2 *= inv;
            const float tr3 = (v0 * v0 + v1 * v1 + v2 * v2) * (1.0f / 3.0f);
            const float y00 = v0 * v0 - tr3, y11 = v1 * v1 - tr3, y22 = v2 * v2 - tr3;
            const float y01 = v0 * v1, y02 = v0 * v2, y12 = v1 * v2;

            const int si = src[ec], di = dst[ec];
            const float az = P1[(size_t)si * 32 + c] + P2[(size_t)di * 32 + c];

            const float a1v = t0 + bd1r;
            const float a2v = t1 + bd2r;
            const float a3v = t2 + bd3r;
            const float a4v = t3 + be3r;
            const float w1v = a1v * C, w2v = a2v * C, w3v = a3v * C;
            const float fI = az * w1v, fA = az * w2v, fS = az * w3v;

            if (val) {
                efeat[(size_t)e * 32 + c] = a4v;
                float* ap = acc + (size_t)di * 320 + c;
                atomAddF(ap,       fI);
                atomAddF(ap + 32,  fA * v0);
                atomAddF(ap + 64,  fA * v1);
                atomAddF(ap + 96,  fA * v2);
                atomAddF(ap + 128, fS * y00);
                atomAddF(ap + 160, fS * y01);
                atomAddF(ap + 192, fS * y02);
                atomAddF(ap + 224, fS * y11);
                atomAddF(ap + 256, fS * y12);
                atomAddF(ap + 288, fS * y22);
            }
        }
    }
}

// ---------------------------------------------------------------------------
// Node kernel: 8 nodes/block, 32 threads (=channels) per node. (unchanged)
// ---------------------------------------------------------------------------
__global__ __launch_bounds__(256) void node_kernel(
    const float* __restrict__ acc,          // [N][10][32]
    const float* __restrict__ Wt0, const float* __restrict__ Wt1, const float* __restrict__ Wt2,
    const float* __restrict__ Ws1, const float* __restrict__ bs1,
    const float* __restrict__ Ws2, const float* __restrict__ bs2,
    const float* __restrict__ lng, const float* __restrict__ lnb,
    float* __restrict__ xout,               // [N][32][3][3]
    int N)
{
    __shared__ float wt[3][32][32];
    __shared__ float ws1[32][64];
    __shared__ float ws2[64][96];
    __shared__ float sb1[64], sb2[96], sg[32], sbv[32];
    __shared__ float accS[NPB][10][32];
    __shared__ float nrmS[NPB][32];
    __shared__ float h1S[NPB][64];

    const int tid = threadIdx.x;
    for (int i = tid; i < 1024; i += 256) wt[0][i >> 5][i & 31] = Wt0[i];
    for (int i = tid; i < 1024; i += 256) wt[1][i >> 5][i & 31] = Wt1[i];
    for (int i = tid; i < 1024; i += 256) wt[2][i >> 5][i & 31] = Wt2[i];
    for (int i = tid; i < 2048; i += 256) ws1[i >> 6][i & 63] = Ws1[i];
    for (int i = tid; i < 6144; i += 256) ws2[i / 96][i % 96] = Ws2[i];
    if (tid < 64) sb1[tid] = bs1[tid];
    if (tid < 96) sb2[tid] = bs2[tid];
    if (tid < 32) { sg[tid] = lng[tid]; sbv[tid] = lnb[tid]; }
    __syncthreads();

    const int ln_ = tid >> 5, u = tid & 31;
    const int n = blockIdx.x * NPB + ln_;
    const bool valid = n < N;

    float c0 = 0, a0 = 0, a1 = 0, a2 = 0, s00 = 0, s01 = 0, s02 = 0, s11 = 0, s12 = 0, s22 = 0;
    if (valid) {
        const float* ap = acc + (size_t)n * 320 + u;
        c0 = ap[0];  a0 = ap[32];  a1 = ap[64];  a2 = ap[96];
        s00 = ap[128]; s01 = ap[160]; s02 = ap[192];
        s11 = ap[224]; s12 = ap[256]; s22 = ap[288];
    }
    accS[ln_][0][u] = c0;  accS[ln_][1][u] = a0;  accS[ln_][2][u] = a1;  accS[ln_][3][u] = a2;
    accS[ln_][4][u] = s00; accS[ln_][5][u] = s01; accS[ln_][6][u] = s02;
    accS[ln_][7][u] = s11; accS[ln_][8][u] = s12; accS[ln_][9][u] = s22;

    float m00 = c0 + s00, m11 = c0 + s11, m22 = c0 + s22;
    float nrm = m00 * m00 + m11 * m11 + m22 * m22
              + 2.0f * (s01 * s01 + a2 * a2 + s02 * s02 + a1 * a1 + s12 * s12 + a0 * a0);

    float sum = nrm;
#pragma unroll
    for (int o = 16; o >= 1; o >>= 1) sum += __shfl_xor(sum, o, 32);
    float mu = sum * (1.0f / 32.0f);
    float dv = nrm - mu;
    float vs = dv * dv;
#pragma unroll
    for (int o = 16; o >= 1; o >>= 1) vs += __shfl_xor(vs, o, 32);
    float var = vs * (1.0f / 32.0f);
    float nl = dv * rsqrtf(var + 1e-5f) * sg[u] + sbv[u];
    nrmS[ln_][u] = nl;
    __syncthreads();

    float h1a = sb1[u], h1b = sb1[u + 32];
#pragma unroll
    for (int k = 0; k < 32; ++k) {
        float x = nrmS[ln_][k];
        h1a += x * ws1[k][u];
        h1b += x * ws1[k][u + 32];
    }
    h1a = h1a / (1.0f + __expf(-h1a));
    h1b = h1b / (1.0f + __expf(-h1b));
    h1S[ln_][u] = h1a; h1S[ln_][u + 32] = h1b;
    __syncthreads();

    float f0 = sb2[3 * u], f1 = sb2[3 * u + 1], f2 = sb2[3 * u + 2];
#pragma unroll
    for (int k = 0; k < 64; ++k) {
        float hh = h1S[ln_][k];
        f0 += hh * ws2[k][3 * u];
        f1 += hh * ws2[k][3 * u + 1];
        f2 += hh * ws2[k][3 * u + 2];
    }
    f0 = f0 / (1.0f + __expf(-f0));
    f1 = f1 / (1.0f + __expf(-f1));
    f2 = f2 / (1.0f + __expf(-f2));

    float m0 = 0, ma0 = 0, ma1 = 0, ma2 = 0;
    float ms00 = 0, ms01 = 0, ms02 = 0, ms11 = 0, ms12 = 0, ms22 = 0;
#pragma unroll
    for (int k = 0; k < 32; ++k) {
        float w0 = wt[0][k][u], w1 = wt[1][k][u], w2 = wt[2][k][u];
        m0   += accS[ln_][0][k] * w0;
        ma0  += accS[ln_][1][k] * w1;
        ma1  += accS[ln_][2][k] * w1;
        ma2  += accS[ln_][3][k] * w1;
        ms00 += accS[ln_][4][k] * w2;
        ms01 += accS[ln_][5][k] * w2;
        ms02 += accS[ln_][6][k] * w2;
        ms11 += accS[ln_][7][k] * w2;
        ms12 += accS[ln_][8][k] * w2;
        ms22 += accS[ln_][9][k] * w2;
    }
    if (valid) {
        float* xp = xout + (size_t)n * 288 + u * 9;
        xp[0] = f0 * m0 + f2 * ms00;
        xp[1] = f1 * (-ma2) + f2 * ms01;
        xp[2] = f1 * ( ma1) + f2 * ms02;
        xp[3] = f1 * ( ma2) + f2 * ms01;
        xp[4] = f0 * m0 + f2 * ms11;
        xp[5] = f1 * (-ma0) + f2 * ms12;
        xp[6] = f1 * (-ma1) + f2 * ms02;
        xp[7] = f1 * ( ma0) + f2 * ms12;
        xp[8] = f0 * m0 + f2 * ms22;
    }
}

extern "C" void kernel_launch(void* const* d_in, const int* in_sizes, int n_in,
                              void* d_out, int out_size, void* d_ws, size_t ws_size,
                              hipStream_t stream) {
    const int N = in_sizes[0];
    const int E = in_sizes[2];

    // Workspace layout (fp32): acc N*320 | P1 N*32 | P2 N*32 | Pt1 95*32 | Pt2 95*32
    float* acc = (float*)d_ws;
    float* P1  = acc + (size_t)N * 320;
    float* P2  = P1 + (size_t)N * 32;
    float* Pt1 = P2 + (size_t)N * 32;
    float* Pt2 = Pt1 + 95 * 32;

    float* xout  = (float*)d_out;              // [N][32][3][3] f32
    float* efeat = xout + (size_t)N * 288;     // [E][32] f32

    ptype_kernel<<<1, 256, 0, stream>>>(
        (const float*)d_in[6], (const float*)d_in[13], (const float*)d_in[14], Pt1, Pt2);

    prep_zero<<<(N * 320 + 255) / 256, 256, 0, stream>>>(
        (const int*)d_in[0], Pt1, Pt2, acc, P1, P2, N);

    edge_kernel<<<1024, 256, 0, stream>>>(
        (const float*)d_in[1], (const float*)d_in[2], (const float*)d_in[3],
        (const int*)d_in[4], (const int*)d_in[5],
        (const float*)d_in[7],  (const float*)d_in[8],
        (const float*)d_in[9],  (const float*)d_in[10],
        (const float*)d_in[11], (const float*)d_in[12],
        (const float*)d_in[15], (const float*)d_in[16],
        P1, P2, acc, efeat, E);

    node_kernel<<<(N + NPB - 1) / NPB, 256, 0, stream>>>(
        acc,
        (const float*)d_in[17], (const float*)d_in[18], (const float*)d_in[19],
        (const float*)d_in[20], (const float*)d_in[21],
        (const float*)d_in[22], (const float*)d_in[23],
        (const float*)d_in[24], (const float*)d_in[25],
        xout, N);
}